// Round 11
// baseline (469.490 us; speedup 1.0000x reference)
//
#include <hip/hip_runtime.h>
#include <math.h>

#define N_NODES 100000
#define N_EDGES 800000
#define DIM_IN 128
#define DIM_OUT 256
#define GRID 512             // co-resident: 2 blocks/CU x 256 CUs
#define BLK 512              // 8 waves
#define GSZ (GRID * BLK)     // 262144 threads
#define TILES 1563           // ceil(100000 / 64) 64-node GEMM tiles
#define SCAN_BLKS 196        // ceil(100000 / 512)

typedef __bf16 bf16x8 __attribute__((ext_vector_type(8)));
typedef float  f32x4  __attribute__((ext_vector_type(4)));

// ---------------- init: zero counts | state | barriers ---------------------
__global__ __launch_bounds__(1024) void k_init(int* __restrict__ p) {
    int i = blockIdx.x * 1024 + threadIdx.x;
    if (i < N_NODES + GRID + 16) p[i] = 0;
}

// ---------------- helpers ---------------------------------------------------
__device__ __forceinline__ float bflo(unsigned u) {
    return __builtin_bit_cast(float, u << 16);
}
__device__ __forceinline__ float bfhi(unsigned u) {
    return __builtin_bit_cast(float, u & 0xffff0000u);
}
__device__ __forceinline__ float gelu_f(float h) {
    float u = h * h;
    float inner = h * (0.7978845608f + 0.0356774081f * u);
    float a = __builtin_amdgcn_exp2f(-2.8853900818f * __builtin_fabsf(inner));
    float t = (1.f - a) * __builtin_amdgcn_rcpf(1.f + a);
    t = __builtin_copysignf(t, inner);
    return 0.5f * h * (1.f + t);
}

// Software grid barrier. Safe because all GRID blocks are co-resident
// (launch_bounds caps VGPR<=128 -> 16 waves/CU -> 2 blocks/CU x 256 CU = 512).
// Agent-scope acq_rel gives cross-XCD L2 writeback/invalidate (same mechanism
// as cooperative-groups grid.sync on gfx94x+).
__device__ __forceinline__ void gbar(unsigned* bar) {
    __syncthreads();
    if (threadIdx.x == 0) {
        __hip_atomic_fetch_add(bar, 1u, __ATOMIC_ACQ_REL, __HIP_MEMORY_SCOPE_AGENT);
        while (__hip_atomic_load(bar, __ATOMIC_ACQUIRE, __HIP_MEMORY_SCOPE_AGENT)
               < (unsigned)GRID) {
            __builtin_amdgcn_s_sleep(2);
        }
    }
    __syncthreads();
}

// ---------------- mega kernel: cvt+count | scan | fill | agg | gemm --------
__global__ __launch_bounds__(BLK, 4) void k_mega(
    const float* __restrict__ x, const float* __restrict__ W,
    const int* __restrict__ src, const int* __restrict__ dst,
    const float* __restrict__ deg_inv, const float* __restrict__ bias,
    unsigned short* __restrict__ xb, unsigned short* __restrict__ Wb,
    unsigned short* __restrict__ mb,
    int* __restrict__ counts, unsigned* __restrict__ state,
    unsigned* __restrict__ bars,
    int* __restrict__ incl, int* __restrict__ cursor, int* __restrict__ csr,
    float* __restrict__ out)
{
    __shared__ int ws8[8];
    __shared__ int sExc;

    const int tid  = threadIdx.x;
    const int bid  = blockIdx.x;
    const int gid  = bid * BLK + tid;
    const int lane = tid & 63;
    const int wid  = tid >> 6;

    // ===== Phase A: cvtX (f32->bf16 packed), cvtW, dst-count ===============
    for (int i = gid; i < N_NODES * DIM_IN / 4; i += GSZ) {
        const float4 v = reinterpret_cast<const float4*>(x)[i];
        unsigned short s0 = __builtin_bit_cast(unsigned short, (__bf16)v.x);
        unsigned short s1 = __builtin_bit_cast(unsigned short, (__bf16)v.y);
        unsigned short s2 = __builtin_bit_cast(unsigned short, (__bf16)v.z);
        unsigned short s3 = __builtin_bit_cast(unsigned short, (__bf16)v.w);
        uint2 o;
        o.x = (unsigned)s0 | ((unsigned)s1 << 16);
        o.y = (unsigned)s2 | ((unsigned)s3 << 16);
        reinterpret_cast<uint2*>(xb)[i] = o;
    }
    if (gid < DIM_IN * DIM_OUT)
        Wb[gid] = __builtin_bit_cast(unsigned short, (__bf16)W[gid]);
    for (int e = gid; e < N_EDGES; e += GSZ)
        atomicAdd(&counts[dst[e]], 1);
    gbar(bars + 0);

    // ===== Phase B: decoupled-lookback scan (chunk 512/block) ==============
    if (bid < SCAN_BLKS) {
        const int i = bid * BLK + tid;
        const int c = (i < N_NODES) ? counts[i] : 0;
        int v = c;
#pragma unroll
        for (int d2 = 1; d2 < 64; d2 <<= 1) {
            int t = __shfl_up(v, d2, 64);
            if (lane >= d2) v += t;
        }
        if (lane == 63) ws8[wid] = v;
        __syncthreads();
        if (wid == 0) {
            int s = (lane < 8) ? ws8[lane] : 0;
#pragma unroll
            for (int d2 = 1; d2 < 8; d2 <<= 1) {
                int t = __shfl_up(s, d2, 64);
                if (lane >= d2) s += t;
            }
            if (lane < 8) ws8[lane] = s;
        }
        __syncthreads();
        const int total = ws8[7];
        if (wid > 0) v += ws8[wid - 1];
        if (tid == 0 && bid > 0)
            __hip_atomic_store(&state[bid], (1u << 30) | (unsigned)total,
                               __ATOMIC_RELEASE, __HIP_MEMORY_SCOPE_AGENT);
        if (wid == 0) {
            int exclusive = 0;
            if (bid > 0) {
                int look = bid - 1;
                for (;;) {
                    int idx = look - lane;
                    unsigned s;
                    bool rdy;
                    do {
                        s = (idx >= 0) ? __hip_atomic_load(&state[idx], __ATOMIC_ACQUIRE,
                                                           __HIP_MEMORY_SCOPE_AGENT)
                                       : (2u << 30);
                        rdy = (s >> 30) != 0u;
                    } while (!__all(rdy));
                    unsigned long long incmask = __ballot((s >> 30) == 2u);
                    int firstInc = (incmask == 0ull) ? 64 : (__ffsll(incmask) - 1);
                    int contrib = (lane <= firstInc) ? (int)(s & 0x3FFFFFFFu) : 0;
#pragma unroll
                    for (int d2 = 32; d2 >= 1; d2 >>= 1)
                        contrib += __shfl_down(contrib, d2, 64);
                    contrib = __shfl(contrib, 0, 64);
                    exclusive += contrib;
                    if (firstInc < 64) break;
                    look -= 64;
                }
            }
            if (lane == 0) {
                sExc = exclusive;
                __hip_atomic_store(&state[bid],
                                   (2u << 30) | (unsigned)(exclusive + total),
                                   __ATOMIC_RELEASE, __HIP_MEMORY_SCOPE_AGENT);
            }
        }
        __syncthreads();
        v += sExc;
        if (i < N_NODES) {
            incl[i] = v;
            cursor[i] = v - c;
        }
    }
    gbar(bars + 1);

    // ===== Phase C: CSR fill ================================================
    for (int e = gid; e < N_EDGES; e += GSZ) {
        int pos = atomicAdd(&cursor[dst[e]], 1);
        csr[pos] = src[e];
    }
    gbar(bars + 2);

    // ===== Phase D: aggregate (wave per node, grid-stride) =================
    for (int node = bid * 8 + wid; node < N_NODES; node += GRID * 8) {
        int end = __builtin_amdgcn_readfirstlane(incl[node]);
        int beg = end - __builtin_amdgcn_readfirstlane(counts[node]);
        float a0 = 0.f, a1 = 0.f, b0 = 0.f, b1 = 0.f;
        float c0 = 0.f, c1 = 0.f, d0 = 0.f, d1 = 0.f;
        int e = beg;
        for (; e + 7 < end; e += 8) {
            int s0 = csr[e],     s1 = csr[e + 1], s2 = csr[e + 2], s3 = csr[e + 3];
            int s4 = csr[e + 4], s5 = csr[e + 5], s6 = csr[e + 6], s7 = csr[e + 7];
            unsigned u0 = reinterpret_cast<const unsigned*>(xb + (size_t)s0 * DIM_IN)[lane];
            unsigned u1 = reinterpret_cast<const unsigned*>(xb + (size_t)s1 * DIM_IN)[lane];
            unsigned u2 = reinterpret_cast<const unsigned*>(xb + (size_t)s2 * DIM_IN)[lane];
            unsigned u3 = reinterpret_cast<const unsigned*>(xb + (size_t)s3 * DIM_IN)[lane];
            unsigned u4 = reinterpret_cast<const unsigned*>(xb + (size_t)s4 * DIM_IN)[lane];
            unsigned u5 = reinterpret_cast<const unsigned*>(xb + (size_t)s5 * DIM_IN)[lane];
            unsigned u6 = reinterpret_cast<const unsigned*>(xb + (size_t)s6 * DIM_IN)[lane];
            unsigned u7 = reinterpret_cast<const unsigned*>(xb + (size_t)s7 * DIM_IN)[lane];
            a0 += bflo(u0) + bflo(u1);  a1 += bfhi(u0) + bfhi(u1);
            b0 += bflo(u2) + bflo(u3);  b1 += bfhi(u2) + bfhi(u3);
            c0 += bflo(u4) + bflo(u5);  c1 += bfhi(u4) + bfhi(u5);
            d0 += bflo(u6) + bflo(u7);  d1 += bfhi(u6) + bfhi(u7);
        }
        for (; e + 3 < end; e += 4) {
            int s0 = csr[e], s1 = csr[e + 1], s2 = csr[e + 2], s3 = csr[e + 3];
            unsigned u0 = reinterpret_cast<const unsigned*>(xb + (size_t)s0 * DIM_IN)[lane];
            unsigned u1 = reinterpret_cast<const unsigned*>(xb + (size_t)s1 * DIM_IN)[lane];
            unsigned u2 = reinterpret_cast<const unsigned*>(xb + (size_t)s2 * DIM_IN)[lane];
            unsigned u3 = reinterpret_cast<const unsigned*>(xb + (size_t)s3 * DIM_IN)[lane];
            a0 += bflo(u0) + bflo(u1);  a1 += bfhi(u0) + bfhi(u1);
            b0 += bflo(u2) + bflo(u3);  b1 += bfhi(u2) + bfhi(u3);
        }
        for (; e < end; ++e) {
            int s0 = csr[e];
            unsigned u0 = reinterpret_cast<const unsigned*>(xb + (size_t)s0 * DIM_IN)[lane];
            a0 += bflo(u0);
            a1 += bfhi(u0);
        }
        float d = deg_inv[node];
        float r0 = ((a0 + b0) + (c0 + d0)) * d;
        float r1 = ((a1 + b1) + (c1 + d1)) * d;
        unsigned short q0 = __builtin_bit_cast(unsigned short, (__bf16)r0);
        unsigned short q1 = __builtin_bit_cast(unsigned short, (__bf16)r1);
        reinterpret_cast<unsigned*>(mb + (size_t)node * DIM_IN)[lane] =
            (unsigned)q0 | ((unsigned)q1 << 16);
    }
    gbar(bars + 3);

    // ===== Phase E: MFMA GEMM + bias + GELU (grid-stride 64-node tiles) ====
    {
        const int lr = lane & 15;
        const int kg = lane >> 4;
        const int o0 = wid * 32;

        bf16x8 wfr[2][4];
#pragma unroll
        for (int mt = 0; mt < 2; ++mt)
#pragma unroll
            for (int ks = 0; ks < 4; ++ks)
                wfr[mt][ks] = *reinterpret_cast<const bf16x8*>(
                    Wb + (size_t)(o0 + mt * 16 + lr) * DIM_IN + ks * 32 + kg * 8);

        f32x4 bias4[2];
#pragma unroll
        for (int mt = 0; mt < 2; ++mt)
            bias4[mt] = *reinterpret_cast<const f32x4*>(bias + o0 + mt * 16 + kg * 4);

        for (int t = bid; t < TILES; t += GRID) {
            const int nb0 = t * 64;
#pragma unroll
            for (int st = 0; st < 2; ++st) {
                const int nb = nb0 + st * 32;
                if (nb >= N_NODES) break;

                bf16x8 mfr[2][4];
#pragma unroll
                for (int nt = 0; nt < 2; ++nt) {
                    const unsigned short* brow = mb + (size_t)(nb + nt * 16 + lr) * DIM_IN;
#pragma unroll
                    for (int ks = 0; ks < 4; ++ks)
                        mfr[nt][ks] = *reinterpret_cast<const bf16x8*>(brow + ks * 32 + kg * 8);
                }

                f32x4 acc[2][2] = {};
#pragma unroll
                for (int ks = 0; ks < 4; ++ks)
#pragma unroll
                    for (int mt = 0; mt < 2; ++mt)
#pragma unroll
                        for (int nt = 0; nt < 2; ++nt)
                            acc[mt][nt] = __builtin_amdgcn_mfma_f32_16x16x32_bf16(
                                wfr[mt][ks], mfr[nt][ks], acc[mt][nt], 0, 0, 0);

#pragma unroll
                for (int nt = 0; nt < 2; ++nt) {
                    const int node = nb + nt * 16 + lr;
                    float* orow = out + (size_t)node * DIM_OUT + o0 + kg * 4;
#pragma unroll
                    for (int mt = 0; mt < 2; ++mt) {
                        f32x4 h = acc[mt][nt] + bias4[mt];
                        f32x4 g;
                        g[0] = gelu_f(h[0]);
                        g[1] = gelu_f(h[1]);
                        g[2] = gelu_f(h[2]);
                        g[3] = gelu_f(h[3]);
                        *reinterpret_cast<f32x4*>(orow + mt * 16) = g;
                    }
                }
            }
        }
    }
}

extern "C" void kernel_launch(void* const* d_in, const int* in_sizes, int n_in,
                              void* d_out, int out_size, void* d_ws, size_t ws_size,
                              hipStream_t stream) {
    const float* x       = (const float*)d_in[0];
    const int*   ei      = (const int*)d_in[1];
    const float* deg_inv = (const float*)d_in[2];
    const float* W       = (const float*)d_in[3];
    const float* bias    = (const float*)d_in[4];
    float*       out     = (float*)d_out;

    const int* src = ei;
    const int* dst = ei + N_EDGES;

    // ws layout: mb | counts | state(GRID) | bars(16) | incl | cursor | csr | Wb | xb
    unsigned short* mb = (unsigned short*)d_ws;
    int*      counts = (int*)(mb + (size_t)N_NODES * DIM_IN);
    unsigned* state  = (unsigned*)(counts + N_NODES);
    unsigned* bars   = state + GRID;
    int*      incl   = (int*)(bars + 16);
    int*      cursor = incl + N_NODES;
    int*      csr    = cursor + N_NODES;
    unsigned short* Wb = (unsigned short*)(csr + N_EDGES);
    unsigned short* xb = Wb + DIM_IN * DIM_OUT;

    k_init<<<(N_NODES + GRID + 16 + 1023) / 1024, 1024, 0, stream>>>(counts);
    k_mega<<<GRID, BLK, 0, stream>>>(x, W, src, dst, deg_inv, bias,
                                     xb, Wb, mb, counts, state, bars,
                                     incl, cursor, csr, out);
}